// Round 3
// baseline (141.413 us; speedup 1.0000x reference)
//
#include <hip/hip_runtime.h>

typedef __attribute__((ext_vector_type(8))) short short8;
typedef __attribute__((ext_vector_type(4))) float floatx4;

#define CIN  256
#define NSP  2048   // T*H*W
#define COUT 256
#define FF   512

// Module-scope scratch (d_ws unused; the harness's 256 MiB ws poison-fill
// proved unconditional in round 2, so workspace vs globals is perf-neutral).
__device__ unsigned short g_M[COUT * CIN];   // 128 KiB bf16 M = Wout @ Wv
__device__ float g_stats[2 * COUT];          // per-oc sum / sumsq

__device__ __forceinline__ unsigned short f2bf_rne(float f) {
  unsigned int u = __float_as_uint(f);
  u += 0x7fffu + ((u >> 16) & 1u);
  return (unsigned short)(u >> 16);
}

// pack two f32 -> bf16x2 (round-half-up: +0x8000 then take hi16) in 3 VALU
__device__ __forceinline__ unsigned int pack_bf16_hu(float lo, float hi) {
  unsigned int a = __float_as_uint(lo) + 0x8000u;
  unsigned int b = __float_as_uint(hi) + 0x8000u;
  return __builtin_amdgcn_perm(b, a, 0x07060302u);
}

// ---------------------------------------------------------------------------
// K1: M = Wout @ Wv (bf16). 256 blocks (1 row each) x 1024 threads.
// Waves split the f(=512) reduction 4 ways; LDS reduce. Block 0 zeroes stats.
// ---------------------------------------------------------------------------
__global__ __launch_bounds__(1024) void k1_m(
    const float* __restrict__ Wv, const float* __restrict__ Wout)
{
  __shared__ float ws[512];
  __shared__ float red[4][256];
  const int tid = threadIdx.x;
  const int r   = blockIdx.x;
  if (r == 0 && tid < 512) g_stats[tid] = 0.f;
  if (tid < 512) ws[tid] = Wout[(size_t)r * 512 + tid];
  __syncthreads();
  const int c  = tid & 255;
  const int fs = tid >> 8;            // constant per wave -> ws[f] broadcast
  float acc = 0.f;
  #pragma unroll 16
  for (int f0 = 0; f0 < 128; ++f0) {
    int f = fs * 128 + f0;
    acc += ws[f] * Wv[(size_t)f * 256 + c];   // coalesced, L2-hot
  }
  red[fs][c] = acc;
  __syncthreads();
  if (tid < 256) {
    float s = red[0][tid] + red[1][tid] + red[2][tid] + red[3][tid];
    g_M[(size_t)r * 256 + tid] = f2bf_rne(s);
  }
}

// ---------------------------------------------------------------------------
// K2: o = M @ x per batch via bf16 MFMA; B-fragments built in-register from
// f32 x. Fused bias+relu+residual; y(f32) -> out; BN partials -> g_stats.
// 1D grid 1024 blocks, XCD-pinned: b = id&7 so all of batch b's blocks land
// on XCD b (round-robin dispatch) -> x[b] (2 MB) is XCD-L2-resident and the
// 2x ocb re-read of x hits L2 instead of HBM. 16 waves/CU (was 8) to hide
// strided-load latency. Wave tile 64oc x 16n (acc[4][1]).
// ---------------------------------------------------------------------------
__global__ __launch_bounds__(256) void k2_gemm(
    const float* __restrict__ x, const float* __restrict__ bout,
    float* __restrict__ out)
{
  __shared__ float ls[128], lq[128];
  const int tid  = threadIdx.x;
  const int lane = tid & 63;
  const int wave = tid >> 6;
  const int m16  = lane & 15;
  const int q    = lane >> 4;
  const int id   = blockIdx.x;
  const int b    = id & 7;            // XCD pin: batch b -> XCD b
  const int k    = id >> 3;           // 0..127 within batch
  const int nb   = (k & 63) * 32;     // 64 n-blocks of 32
  const int ocb  = (k >> 6) * 128;    // 2 oc-blocks of 128
  const int wocb = ocb + (wave & 1) * 64;   // wave's 64 oc rows
  const int wnb  = nb + (wave >> 1) * 16;   // wave's 16 n cols

  if (tid < 128) { ls[tid] = 0.f; lq[tid] = 0.f; }

  floatx4 acc[4];
  #pragma unroll
  for (int i = 0; i < 4; ++i)
    acc[i] = (floatx4){0.f, 0.f, 0.f, 0.f};

  const unsigned short* Ab = g_M + (size_t)(wocb + m16) * 256 + q * 8;
  const float* xb = x + (size_t)b * CIN * NSP;
  const float* Bb = xb + (size_t)(q * 8) * NSP + wnb + m16;

  #pragma unroll
  for (int kk = 0; kk < 8; ++kk) {
    short8 av[4];
    #pragma unroll
    for (int ti = 0; ti < 4; ++ti)
      av[ti] = *(const short8*)(Ab + (size_t)ti * 16 * 256 + kk * 32);
    const float* bp = Bb + (size_t)(kk * 32) * NSP;
    union { unsigned int u[4]; short8 v; } p;
    #pragma unroll
    for (int j = 0; j < 4; ++j) {
      float f0 = bp[(size_t)(2 * j) * NSP];       // c = kk*32+q*8+2j
      float f1 = bp[(size_t)(2 * j + 1) * NSP];
      p.u[j] = pack_bf16_hu(f0, f1);
    }
    #pragma unroll
    for (int ti = 0; ti < 4; ++ti)
      acc[ti] = __builtin_amdgcn_mfma_f32_16x16x32_bf16(av[ti], p.v, acc[ti], 0, 0, 0);
  }

  __syncthreads();  // ls/lq zeros ready

  // D layout: col(n)=lane&15, row(oc within 16-tile)=q*4+reg
  #pragma unroll
  for (int ti = 0; ti < 4; ++ti) {
    #pragma unroll
    for (int r = 0; r < 4; ++r) {
      const int ocl = (wave & 1) * 64 + ti * 16 + q * 4 + r;
      const int oc  = ocb + ocl;
      const float bo = bout[oc];
      const int n = wnb + m16;
      const size_t gidx = ((size_t)(b * COUT + oc)) * NSP + n;
      float o = fmaxf(acc[ti][r] + bo, 0.f);
      float y = x[gidx] + o;          // residual: row is XCD-L2-hot (B-loads)
      out[gidx] = y;                  // f32, 64B sectors per 16-lane group
      float s = y, s2 = y * y;
      #pragma unroll
      for (int d = 1; d < 16; d <<= 1) {  // stays within 16-lane group
        s  += __shfl_xor(s, d, 64);
        s2 += __shfl_xor(s2, d, 64);
      }
      if (m16 == 0) {
        atomicAdd(&ls[ocl], s);
        atomicAdd(&lq[ocl], s2);
      }
    }
  }
  __syncthreads();
  if (tid < 128) {
    atomicAdd(&g_stats[ocb + tid], ls[tid]);
    atomicAdd(&g_stats[256 + ocb + tid], lq[tid]);
  }
}

// ---------------------------------------------------------------------------
// K3: normalize out in place. 2048 blocks, XCD-pinned same as K2 (b = id&7)
// so batch b's out rows are re-read from XCD b's L2 (written there by K2).
// ---------------------------------------------------------------------------
__global__ __launch_bounds__(256) void k3_norm(
    const float* __restrict__ gamma, const float* __restrict__ beta,
    float* __restrict__ out)
{
  const int id  = blockIdx.x;
  const int b   = id & 7;             // XCD pin: batch b -> XCD b
  const int oc  = id >> 3;            // 0..255
  const float inv_n = 1.f / 16384.f;
  const float m  = g_stats[oc] * inv_n;
  const float v  = g_stats[256 + oc] * inv_n - m * m;
  const float sc = gamma[oc] * rsqrtf(v + 1e-5f);
  const float sh = beta[oc] - m * sc;
  float* p = out + ((size_t)(b * COUT + oc)) * NSP + threadIdx.x * 8;
  float4 a = *(const float4*)p;
  float4 c = *(const float4*)(p + 4);
  a.x = a.x * sc + sh; a.y = a.y * sc + sh;
  a.z = a.z * sc + sh; a.w = a.w * sc + sh;
  c.x = c.x * sc + sh; c.y = c.y * sc + sh;
  c.z = c.z * sc + sh; c.w = c.w * sc + sh;
  *(float4*)p = a;
  *(float4*)(p + 4) = c;
}

extern "C" void kernel_launch(void* const* d_in, const int* in_sizes, int n_in,
                              void* d_out, int out_size, void* d_ws, size_t ws_size,
                              hipStream_t stream) {
  const float* x     = (const float*)d_in[0];
  // d_in[1]=Wk, d_in[2]=Wq: dead — softmax rows sum to 1, so agg == V,
  // and o = Wout@(Wv@x) = (Wout@Wv)@x = M@x.
  const float* Wv    = (const float*)d_in[3];
  const float* Wout  = (const float*)d_in[4];
  const float* bout  = (const float*)d_in[5];
  const float* gamma = (const float*)d_in[6];
  const float* beta  = (const float*)d_in[7];
  float* out = (float*)d_out;

  hipLaunchKernelGGL(k1_m,    dim3(256),  dim3(1024), 0, stream, Wv, Wout);
  hipLaunchKernelGGL(k2_gemm, dim3(1024), dim3(256),  0, stream, x, bout, out);
  hipLaunchKernelGGL(k3_norm, dim3(2048), dim3(256),  0, stream,
                     gamma, beta, out);
}

// Round 4
// 116.396 us; speedup vs baseline: 1.2149x; 1.2149x over previous
//
#include <hip/hip_runtime.h>

typedef __attribute__((ext_vector_type(8))) short short8;
typedef __attribute__((ext_vector_type(4))) float floatx4;

#define CIN  256
#define NSP  2048   // T*H*W
#define COUT 256
#define FF   512
#define NSHARD 32

// Module-scope scratch (d_ws unused; the harness's 256 MiB ws poison-fill
// proved unconditional in round 2, so workspace vs globals is perf-neutral).
__device__ unsigned short g_M[COUT * CIN];        // 128 KiB bf16 M = Wout @ Wv
// Sharded BN partials: 32 shards x {sum, sumsq} x 256 oc. Sharding cuts
// device-scope atomic contention from 256 adds/address (round-2) to 8.
__device__ float g_shard[NSHARD][2][COUT];        // 64 KiB

__device__ __forceinline__ unsigned short f2bf_rne(float f) {
  unsigned int u = __float_as_uint(f);
  u += 0x7fffu + ((u >> 16) & 1u);
  return (unsigned short)(u >> 16);
}

// pack two f32 -> bf16x2 (round-half-up: +0x8000 then take hi16) in 3 VALU
__device__ __forceinline__ unsigned int pack_bf16_hu(float lo, float hi) {
  unsigned int a = __float_as_uint(lo) + 0x8000u;
  unsigned int b = __float_as_uint(hi) + 0x8000u;
  return __builtin_amdgcn_perm(b, a, 0x07060302u);
}

// ---------------------------------------------------------------------------
// K1: M = Wout @ Wv (bf16). 256 blocks (1 row each) x 1024 threads.
// Waves split the f(=512) reduction 4 ways; LDS reduce. Block 0 zeroes shards.
// ---------------------------------------------------------------------------
__global__ __launch_bounds__(1024) void k1_m(
    const float* __restrict__ Wv, const float* __restrict__ Wout)
{
  __shared__ float ws[512];
  __shared__ float red[4][256];
  const int tid = threadIdx.x;
  const int r   = blockIdx.x;
  if (r == 0) {
    float* gs = &g_shard[0][0][0];    // 16384 floats
    #pragma unroll
    for (int i = 0; i < 16; ++i) gs[tid + i * 1024] = 0.f;
  }
  if (tid < 512) ws[tid] = Wout[(size_t)r * 512 + tid];
  __syncthreads();
  const int c  = tid & 255;
  const int fs = tid >> 8;            // constant per wave -> ws[f] broadcast
  float acc = 0.f;
  #pragma unroll 16
  for (int f0 = 0; f0 < 128; ++f0) {
    int f = fs * 128 + f0;
    acc += ws[f] * Wv[(size_t)f * 256 + c];   // coalesced, L2-hot
  }
  red[fs][c] = acc;
  __syncthreads();
  if (tid < 256) {
    float s = red[0][tid] + red[1][tid] + red[2][tid] + red[3][tid];
    g_M[(size_t)r * 256 + tid] = f2bf_rne(s);
  }
}

// ---------------------------------------------------------------------------
// K2: o = M @ x per batch via bf16 MFMA; B-fragments built in-register from
// f32 x (no transpose pass, no LDS staging, no K-loop barriers).
// Fused bias+relu+residual; f32 y -> out; BN partials -> g_shard (sharded).
// grid (32 nb, 2 ocb, 8 b) = 512 blocks; block = 4 waves; wave tile 64oc x 32n.
// __launch_bounds__(256,2): grid is 2 blocks/CU, so allow up to 256 VGPR --
// gives the fully-unrolled K-loop headroom to keep all 8 kk loads in flight
// (round-3 build had VGPR_Count=40 -> serialized load-waits every kk).
// ---------------------------------------------------------------------------
__global__ __launch_bounds__(256, 2) void k2_gemm(
    const float* __restrict__ x, const float* __restrict__ bout,
    float* __restrict__ out)
{
  __shared__ float ls[128], lq[128];
  const int tid  = threadIdx.x;
  const int lane = tid & 63;
  const int wave = tid >> 6;
  const int m16  = lane & 15;
  const int q    = lane >> 4;
  const int nb   = blockIdx.x * 64;
  const int ocb  = blockIdx.y * 128;
  const int b    = blockIdx.z;
  const int wocb = ocb + (wave & 1) * 64;   // wave's 64 oc rows
  const int wnb  = nb + (wave >> 1) * 32;   // wave's 32 n cols

  if (tid < 128) { ls[tid] = 0.f; lq[tid] = 0.f; }

  floatx4 acc[4][2];
  #pragma unroll
  for (int i = 0; i < 4; ++i)
    #pragma unroll
    for (int j = 0; j < 2; ++j)
      acc[i][j] = (floatx4){0.f, 0.f, 0.f, 0.f};

  const unsigned short* Ab = g_M + (size_t)(wocb + m16) * 256 + q * 8;
  const float* xb = x + (size_t)b * CIN * NSP;
  const float* Bb = xb + (size_t)(q * 8) * NSP + wnb + m16;

  #pragma unroll
  for (int kk = 0; kk < 8; ++kk) {
    short8 av[4];
    #pragma unroll
    for (int ti = 0; ti < 4; ++ti)
      av[ti] = *(const short8*)(Ab + (size_t)ti * 16 * 256 + kk * 32);
    short8 bv[2];
    #pragma unroll
    for (int tj = 0; tj < 2; ++tj) {
      const float* bp = Bb + (size_t)(kk * 32) * NSP + tj * 16;
      union { unsigned int u[4]; short8 v; } p;
      #pragma unroll
      for (int j = 0; j < 4; ++j) {
        float f0 = bp[(size_t)(2 * j) * NSP];       // c = kk*32+q*8+2j
        float f1 = bp[(size_t)(2 * j + 1) * NSP];
        p.u[j] = pack_bf16_hu(f0, f1);
      }
      bv[tj] = p.v;
    }
    #pragma unroll
    for (int ti = 0; ti < 4; ++ti)
      #pragma unroll
      for (int tj = 0; tj < 2; ++tj)
        acc[ti][tj] = __builtin_amdgcn_mfma_f32_16x16x32_bf16(av[ti], bv[tj], acc[ti][tj], 0, 0, 0);
  }

  __syncthreads();  // ls/lq zeros ready

  // D layout: col(n)=lane&15, row(oc within 16-tile)=q*4+reg
  #pragma unroll
  for (int ti = 0; ti < 4; ++ti) {
    #pragma unroll
    for (int r = 0; r < 4; ++r) {
      const int ocl = (wave & 1) * 64 + ti * 16 + q * 4 + r;
      const int oc  = ocb + ocl;
      const float bo = bout[oc];
      float s = 0.f, s2 = 0.f;
      #pragma unroll
      for (int tj = 0; tj < 2; ++tj) {
        const int n = wnb + tj * 16 + m16;
        const size_t gidx = ((size_t)(b * COUT + oc)) * NSP + n;
        float o = fmaxf(acc[ti][tj][r] + bo, 0.f);
        float y = x[gidx] + o;        // residual: row is L1/L2-hot (B-loads)
        out[gidx] = y;                // f32, full 64B sectors per quad
        s += y;
        s2 += y * y;
      }
      #pragma unroll
      for (int d = 1; d < 16; d <<= 1) {  // stays within 16-lane group
        s  += __shfl_xor(s, d, 64);
        s2 += __shfl_xor(s2, d, 64);
      }
      if (m16 == 0) {
        atomicAdd(&ls[ocl], s);
        atomicAdd(&lq[ocl], s2);
      }
    }
  }
  __syncthreads();
  if (tid < 128) {
    const int s = blockIdx.x;         // 32 shards; 8 atomics/address (8 b's)
    atomicAdd(&g_shard[s][0][ocb + tid], ls[tid]);
    atomicAdd(&g_shard[s][1][ocb + tid], lq[tid]);
  }
}

// ---------------------------------------------------------------------------
// K3: normalize out in place. 2048 blocks = one (b,oc) row of 2048 each.
// Shard sum (32x {sum,sq}) is uniform per block -> scalar-path broadcast
// loads, all L2-hot (64 KiB). scale/shift computed redundantly per thread.
// ---------------------------------------------------------------------------
__global__ __launch_bounds__(256) void k3_norm(
    const float* __restrict__ gamma, const float* __restrict__ beta,
    float* __restrict__ out)
{
  const int row = blockIdx.x;       // b*256 + oc
  const int oc  = row & 255;
  float su = 0.f, sq = 0.f;
  #pragma unroll
  for (int i = 0; i < NSHARD; ++i) {
    su += g_shard[i][0][oc];
    sq += g_shard[i][1][oc];
  }
  const float inv_n = 1.f / 16384.f;
  const float m  = su * inv_n;
  const float v  = sq * inv_n - m * m;
  const float sc = gamma[oc] * rsqrtf(v + 1e-5f);
  const float sh = beta[oc] - m * sc;
  float* p = out + (size_t)row * 2048 + threadIdx.x * 8;
  float4 a = *(const float4*)p;
  float4 c = *(const float4*)(p + 4);
  a.x = a.x * sc + sh; a.y = a.y * sc + sh;
  a.z = a.z * sc + sh; a.w = a.w * sc + sh;
  c.x = c.x * sc + sh; c.y = c.y * sc + sh;
  c.z = c.z * sc + sh; c.w = c.w * sc + sh;
  *(float4*)p = a;
  *(float4*)(p + 4) = c;
}

extern "C" void kernel_launch(void* const* d_in, const int* in_sizes, int n_in,
                              void* d_out, int out_size, void* d_ws, size_t ws_size,
                              hipStream_t stream) {
  const float* x     = (const float*)d_in[0];
  // d_in[1]=Wk, d_in[2]=Wq: dead — softmax rows sum to 1, so agg == V,
  // and o = Wout@(Wv@x) = (Wout@Wv)@x = M@x.
  const float* Wv    = (const float*)d_in[3];
  const float* Wout  = (const float*)d_in[4];
  const float* bout  = (const float*)d_in[5];
  const float* gamma = (const float*)d_in[6];
  const float* beta  = (const float*)d_in[7];
  float* out = (float*)d_out;

  hipLaunchKernelGGL(k1_m,    dim3(256),       dim3(1024), 0, stream,
                     Wv, Wout);
  hipLaunchKernelGGL(k2_gemm, dim3(32, 2, 8),  dim3(256),  0, stream,
                     x, bout, out);
  hipLaunchKernelGGL(k3_norm, dim3(2048),      dim3(256),  0, stream,
                     gamma, beta, out);
}

// Round 5
// 113.217 us; speedup vs baseline: 1.2491x; 1.0281x over previous
//
#include <hip/hip_runtime.h>

typedef __attribute__((ext_vector_type(8))) short short8;
typedef __attribute__((ext_vector_type(4))) float floatx4;

#define CIN  256
#define NSP  2048   // T*H*W
#define COUT 256
#define FF   512
#define NSHARD 32
#define LPAD 66     // LDS row pitch in dwords for the 64-wide x panel:
                    // 66 ≡ 2 (mod 32) spreads q-groups to <=2-way banks (free)

// Module-scope scratch (d_ws unused; the harness's 256 MiB ws poison-fill
// proved unconditional in round 2, so workspace vs globals is perf-neutral).
__device__ unsigned short g_M[COUT * CIN];        // 128 KiB bf16 M = Wout @ Wv
// Sharded BN partials: 32 shards x {sum, sumsq} x 256 oc -> 8 atomics/address.
__device__ float g_shard[NSHARD][2][COUT];        // 64 KiB

__device__ __forceinline__ unsigned short f2bf_rne(float f) {
  unsigned int u = __float_as_uint(f);
  u += 0x7fffu + ((u >> 16) & 1u);
  return (unsigned short)(u >> 16);
}

// pack two f32 -> bf16x2 (round-half-up: +0x8000 then take hi16) in 3 VALU
__device__ __forceinline__ unsigned int pack_bf16_hu(float lo, float hi) {
  unsigned int a = __float_as_uint(lo) + 0x8000u;
  unsigned int b = __float_as_uint(hi) + 0x8000u;
  return __builtin_amdgcn_perm(b, a, 0x07060302u);
}

// ---------------------------------------------------------------------------
// K1: M = Wout @ Wv (bf16). 256 blocks (1 row each) x 1024 threads.
// Waves split the f(=512) reduction 4 ways; LDS reduce. Block 0 zeroes shards.
// ---------------------------------------------------------------------------
__global__ __launch_bounds__(1024) void k1_m(
    const float* __restrict__ Wv, const float* __restrict__ Wout)
{
  __shared__ float ws[512];
  __shared__ float red[4][256];
  const int tid = threadIdx.x;
  const int r   = blockIdx.x;
  if (r == 0) {
    float* gs = &g_shard[0][0][0];    // 16384 floats
    #pragma unroll
    for (int i = 0; i < 16; ++i) gs[tid + i * 1024] = 0.f;
  }
  if (tid < 512) ws[tid] = Wout[(size_t)r * 512 + tid];
  __syncthreads();
  const int c  = tid & 255;
  const int fs = tid >> 8;            // constant per wave -> ws[f] broadcast
  float acc = 0.f;
  #pragma unroll 16
  for (int f0 = 0; f0 < 128; ++f0) {
    int f = fs * 128 + f0;
    acc += ws[f] * Wv[(size_t)f * 256 + c];   // coalesced, L2-hot
  }
  red[fs][c] = acc;
  __syncthreads();
  if (tid < 256) {
    float s = red[0][tid] + red[1][tid] + red[2][tid] + red[3][tid];
    g_M[(size_t)r * 256 + tid] = f2bf_rne(s);
  }
}

// ---------------------------------------------------------------------------
// K2: o = M @ x via bf16 MFMA, with the block's x panel STAGED IN LDS.
// 256 blocks x 512 threads; block = full 256 oc x 64 n for one batch.
//   - staging: 8 coalesced float4 loads/thread (was 128 scalar strided 4B
//     loads/thread in the K-loop -- the round-0..4 latency bottleneck).
//   - B-fragments packed from LDS (pitch-66 rows: <=2-way bank aliasing).
//   - residual x[b][oc][n] == staged panel row oc -> LDS read, no 2nd
//     global pass (CIN==COUT).
//   - x HBM fetch 2x -> 1x (block covers both oc halves).
//   - XCD pin: b = id&7 -> batch's panel + g_M stay XCD-L2-local.
// Epilogue: bias+relu+residual, f32 y -> out, BN partials -> g_shard.
// ---------------------------------------------------------------------------
__global__ __launch_bounds__(512, 2) void k2_gemm(
    const float* __restrict__ x, const float* __restrict__ bout,
    float* __restrict__ out)
{
  __shared__ float lx[CIN * LPAD];    // 256 x 66 dwords = 66 KiB
  __shared__ float ls[COUT], lq[COUT];
  const int tid  = threadIdx.x;
  const int lane = tid & 63;
  const int wave = tid >> 6;
  const int m16  = lane & 15;
  const int q    = lane >> 4;
  const int id   = blockIdx.x;
  const int b    = id & 7;            // XCD pin: batch b -> XCD b (256%8==0)
  const int n0   = (id >> 3) * 64;    // 32 n-panels per batch
  const int wocb = (wave & 3) * 64;   // wave's 64 oc rows
  const int wn   = (wave >> 2) * 32;  // wave's 32 n cols (panel-local)

  if (tid < COUT) { ls[tid] = 0.f; lq[tid] = 0.f; }

  // ---- stage x[b][0:256][n0:n0+64] (64 KiB f32) into LDS ----
  {
    const int n4 = (tid & 15) * 4;
    const int cr = tid >> 5;          // 0..15
    const int ch = (tid >> 4) & 1;    // split 256 rows: cr + 16*(i*2+ch)
    const float* gp = x + (size_t)b * CIN * NSP + n0 + n4;
    #pragma unroll
    for (int i = 0; i < 8; ++i) {
      const int c = cr + 16 * (2 * i + ch);
      const float4 v = *(const float4*)(gp + (size_t)c * NSP);
      float* d = &lx[c * LPAD + n4];
      *(float2*)d       = make_float2(v.x, v.y);   // pitch 66 is 8B-aligned
      *(float2*)(d + 2) = make_float2(v.z, v.w);
    }
  }
  __syncthreads();

  floatx4 acc[4][2];
  #pragma unroll
  for (int i = 0; i < 4; ++i)
    #pragma unroll
    for (int j = 0; j < 2; ++j)
      acc[i][j] = (floatx4){0.f, 0.f, 0.f, 0.f};

  const unsigned short* Ab = g_M + (size_t)(wocb + m16) * 256 + q * 8;

  #pragma unroll
  for (int kk = 0; kk < 8; ++kk) {
    short8 av[4];
    #pragma unroll
    for (int ti = 0; ti < 4; ++ti)
      av[ti] = *(const short8*)(Ab + (size_t)ti * 16 * 256 + kk * 32);
    short8 bv[2];
    #pragma unroll
    for (int tj = 0; tj < 2; ++tj) {
      const int nl = wn + tj * 16 + m16;
      const float* lp = &lx[(kk * 32 + q * 8) * LPAD + nl];
      union { unsigned int u[4]; short8 v; } p;
      #pragma unroll
      for (int j = 0; j < 4; ++j) {
        float f0 = lp[(2 * j) * LPAD];        // c = kk*32+q*8+2j
        float f1 = lp[(2 * j + 1) * LPAD];
        p.u[j] = pack_bf16_hu(f0, f1);
      }
      bv[tj] = p.v;
    }
    #pragma unroll
    for (int ti = 0; ti < 4; ++ti)
      #pragma unroll
      for (int tj = 0; tj < 2; ++tj)
        acc[ti][tj] = __builtin_amdgcn_mfma_f32_16x16x32_bf16(av[ti], bv[tj], acc[ti][tj], 0, 0, 0);
  }

  // D layout: col(n)=lane&15, row(oc within 16-tile)=q*4+reg
  #pragma unroll
  for (int ti = 0; ti < 4; ++ti) {
    #pragma unroll
    for (int r = 0; r < 4; ++r) {
      const int oc = wocb + ti * 16 + q * 4 + r;
      const float bo = bout[oc];
      float s = 0.f, s2 = 0.f;
      #pragma unroll
      for (int tj = 0; tj < 2; ++tj) {
        const int nl = wn + tj * 16 + m16;
        const size_t gidx = ((size_t)(b * COUT + oc)) * NSP + n0 + nl;
        float o = fmaxf(acc[ti][tj][r] + bo, 0.f);
        float y = lx[oc * LPAD + nl] + o;   // residual from staged panel
        out[gidx] = y;                      // f32, 64B sectors per quad
        s += y;
        s2 += y * y;
      }
      #pragma unroll
      for (int d = 1; d < 16; d <<= 1) {    // stays within 16-lane group
        s  += __shfl_xor(s, d, 64);
        s2 += __shfl_xor(s2, d, 64);
      }
      if (m16 == 0) {
        atomicAdd(&ls[oc], s);
        atomicAdd(&lq[oc], s2);
      }
    }
  }
  __syncthreads();
  if (tid < COUT) {
    const int s = id >> 3;            // 32 shards; 8 atomics/address (8 b's)
    atomicAdd(&g_shard[s][0][tid], ls[tid]);
    atomicAdd(&g_shard[s][1][tid], lq[tid]);
  }
}

// ---------------------------------------------------------------------------
// K3: normalize out in place. 2048 blocks = one (b,oc) row of 2048 each.
// Shard sum (32x {sum,sq}) is uniform per block -> scalar-path broadcast
// loads, all L2-hot (64 KiB). scale/shift computed redundantly per thread.
// ---------------------------------------------------------------------------
__global__ __launch_bounds__(256) void k3_norm(
    const float* __restrict__ gamma, const float* __restrict__ beta,
    float* __restrict__ out)
{
  const int row = blockIdx.x;       // b*256 + oc
  const int oc  = row & 255;
  float su = 0.f, sq = 0.f;
  #pragma unroll
  for (int i = 0; i < NSHARD; ++i) {
    su += g_shard[i][0][oc];
    sq += g_shard[i][1][oc];
  }
  const float inv_n = 1.f / 16384.f;
  const float m  = su * inv_n;
  const float v  = sq * inv_n - m * m;
  const float sc = gamma[oc] * rsqrtf(v + 1e-5f);
  const float sh = beta[oc] - m * sc;
  float* p = out + (size_t)row * 2048 + threadIdx.x * 8;
  float4 a = *(const float4*)p;
  float4 c = *(const float4*)(p + 4);
  a.x = a.x * sc + sh; a.y = a.y * sc + sh;
  a.z = a.z * sc + sh; a.w = a.w * sc + sh;
  c.x = c.x * sc + sh; c.y = c.y * sc + sh;
  c.z = c.z * sc + sh; c.w = c.w * sc + sh;
  *(float4*)p = a;
  *(float4*)(p + 4) = c;
}

extern "C" void kernel_launch(void* const* d_in, const int* in_sizes, int n_in,
                              void* d_out, int out_size, void* d_ws, size_t ws_size,
                              hipStream_t stream) {
  const float* x     = (const float*)d_in[0];
  // d_in[1]=Wk, d_in[2]=Wq: dead — softmax rows sum to 1, so agg == V,
  // and o = Wout@(Wv@x) = (Wout@Wv)@x = M@x.
  const float* Wv    = (const float*)d_in[3];
  const float* Wout  = (const float*)d_in[4];
  const float* bout  = (const float*)d_in[5];
  const float* gamma = (const float*)d_in[6];
  const float* beta  = (const float*)d_in[7];
  float* out = (float*)d_out;

  hipLaunchKernelGGL(k1_m,    dim3(256),  dim3(1024), 0, stream, Wv, Wout);
  hipLaunchKernelGGL(k2_gemm, dim3(256),  dim3(512),  0, stream, x, bout, out);
  hipLaunchKernelGGL(k3_norm, dim3(2048), dim3(256),  0, stream,
                     gamma, beta, out);
}